// Round 3
// baseline (297.516 us; speedup 1.0000x reference)
//
#include <hip/hip_runtime.h>
#include <hip/hip_cooperative_groups.h>
#include <math.h>

namespace cg = cooperative_groups;

#define N_NODES 50000
#define F 64
#define OUTF 32
#define NX4 (N_NODES * 16)          // float4 count of x
#define NPREP (16384 + 2048 + 128 + 32)
#define CAP 64                      // max in-degree capacity (in-deg ~Poisson(16); P(>64) ~ 1e-19)

#define CH 64                       // edge chunks (both weighted src-deg and dst counts)
#define QS 4                        // node quarters
#define QR 12500                    // nodes per quarter (50 KB LDS)

typedef __bf16 v8bf __attribute__((ext_vector_type(8)));
typedef float v4f __attribute__((ext_vector_type(4)));

static __device__ __forceinline__ unsigned short f2bf(float f) {
    union { float f; unsigned u; } v; v.f = f;
    unsigned r = v.u + 0x7FFFu + ((v.u >> 16) & 1u);   // round-to-nearest-even
    return (unsigned short)(r >> 16);
}
static __device__ __forceinline__ float bf2f(unsigned short h) {
    union { unsigned u; float f; } v; v.u = ((unsigned)h) << 16;
    return v.f;
}

// ============ cooperative preprocessing: pre + hist(W,C) + reduce/prefix + place ============
// 256 blocks x 1024 threads, 50 KB LDS -> 1 block/CU co-resident (well within limits).
// Phase 0: x->bf16 cast + weight prep              (independent)
// Phase 1a: weighted src-degree hist (chunk x quarter, LDS f32 atomics) -> partW
// Phase 1b: dst-count hist           (chunk x quarter, LDS u32 atomics) -> partC (u16)
//   --- grid.sync ---
// Phase 2: deg reduce -> dinv; exclusive prefix of partC over chunks -> offsets + cursor
//   --- grid.sync ---
// Phase 3: deterministic CSR build (LDS cursors, no global atomics) -> rec
__launch_bounds__(1024)
__global__ void coop_kernel(const float4* __restrict__ x4, uint2* __restrict__ xb4,
                            const int* __restrict__ src, const int* __restrict__ dst,
                            const float* __restrict__ ew,
                            const float* __restrict__ Wxz0, const float* __restrict__ Wxz1,
                            const float* __restrict__ Wxh0, const float* __restrict__ Wxh1,
                            const float* __restrict__ Wlin,
                            const float* __restrict__ bxz, const float* __restrict__ bhz,
                            const float* __restrict__ bxh, const float* __restrict__ bhh,
                            const float* __restrict__ blin,
                            unsigned short* __restrict__ Bt, unsigned short* __restrict__ Wlt,
                            float* __restrict__ bzc, float* __restrict__ blc,
                            float* __restrict__ partW, unsigned short* __restrict__ partC,
                            float* __restrict__ dinv, unsigned* __restrict__ cursor,
                            unsigned* __restrict__ rec, int E) {
    __shared__ float smf[QR];            // 50 KB, reused as u32 in phases 1b/3
    unsigned* smu = (unsigned*)smf;

    int tid = threadIdx.x, b = blockIdx.x;
    int gt = b * 1024 + tid;

    // ---- phase 0: pre (grid-stride) ----
    for (int i = gt; i < NX4 + NPREP; i += 256 * 1024) {
        if (i < NX4) {
            float4 v = x4[i];
            uint2 o;
            o.x = (unsigned)f2bf(v.x) | ((unsigned)f2bf(v.y) << 16);
            o.y = (unsigned)f2bf(v.z) | ((unsigned)f2bf(v.w) << 16);
            xb4[i] = o;
        } else {
            int idx = i - NX4;
            if (idx < 16384) {
                int k = idx & 127, n = idx >> 7;
                float v;
                if (k < 64) v = (n < 64) ? Wxz0[k * 64 + n] : Wxh0[k * 64 + (n - 64)];
                else        v = (n < 64) ? Wxz1[(k - 64) * 64 + n] : Wxh1[(k - 64) * 64 + (n - 64)];
                Bt[n * 128 + k] = f2bf(v);
            } else if (idx < 16384 + 2048) {
                int j = idx - 16384; int k = j & 63, n = j >> 6;
                Wlt[n * 64 + k] = f2bf(Wlin[k * 32 + n]);
            } else if (idx < 16384 + 2048 + 128) {
                int j = idx - 16384 - 2048;
                bzc[j] = (j < 64) ? (bxz[j] + bhz[j]) : (bxh[j - 64] + bhh[j - 64]);
            } else if (idx < NPREP) {
                int j = idx - 16384 - 2048 - 128;
                blc[j] = blin[j];
            }
        }
    }

    int chunk = b >> 2, qs = b & 3;
    int nbase = qs * QR;
    int epb = (E + CH - 1) / CH;
    int lo = chunk * epb, hi = min(lo + epb, E);

    // ---- phase 1a: weighted src-degree histogram ----
    for (int i = tid; i < QR; i += 1024) smf[i] = 0.f;
    __syncthreads();
    for (int e = lo + tid; e < hi; e += 1024) {
        int s = src[e];
        unsigned ls = (unsigned)(s - nbase);
        if (ls < QR) atomicAdd(&smf[ls], ew[e]);
    }
    __syncthreads();
    for (int i = tid; i < QR; i += 1024)
        partW[(size_t)chunk * N_NODES + nbase + i] = smf[i];
    __syncthreads();

    // ---- phase 1b: dst-count histogram ----
    for (int i = tid; i < QR; i += 1024) smu[i] = 0u;
    __syncthreads();
    for (int e = lo + tid; e < hi; e += 1024) {
        unsigned ls = (unsigned)(dst[e] - nbase);
        if (ls < QR) atomicAdd(&smu[ls], 1u);
    }
    __syncthreads();
    for (int i = tid; i < QR; i += 1024)
        partC[(size_t)chunk * N_NODES + nbase + i] = (unsigned short)smu[i];

    cg::this_grid().sync();

    // ---- phase 2: reduce deg -> dinv; exclusive prefix partC -> offsets + cursor ----
    if (gt < N_NODES) {
        float s = 0.f;
        #pragma unroll
        for (int c = 0; c < CH; ++c) s += partW[(size_t)c * N_NODES + gt];
        dinv[gt] = s > 0.f ? rsqrtf(s) : 0.f;
        unsigned run = 0u;
        #pragma unroll
        for (int c = 0; c < CH; ++c) {
            unsigned v = partC[(size_t)c * N_NODES + gt];
            partC[(size_t)c * N_NODES + gt] = (unsigned short)run;
            run += v;
        }
        cursor[gt] = run;                   // total in-degree (accum clamps to CAP)
    }

    cg::this_grid().sync();

    // ---- phase 3: place (LDS cursors from offsets, no global atomics) ----
    for (int i = tid; i < QR; i += 1024)
        smu[i] = (unsigned)partC[(size_t)chunk * N_NODES + nbase + i];
    __syncthreads();
    for (int e = lo + tid; e < hi; e += 1024) {
        int d = dst[e];
        unsigned ls = (unsigned)(d - nbase);
        if (ls < QR) {
            int s = src[e];
            float coef = -dinv[s] * ew[e] * dinv[d];
            unsigned pos = atomicAdd(&smu[ls], 1u);   // LDS atomic
            if (pos < CAP)
                rec[((size_t)d << 6) + pos] = (unsigned)s | ((unsigned)f2bf(coef) << 16);
        }
    }
}

// ---------------- accum: one wave per dst node, gather + f32 register accumulate ----------------
// 4 nodes/block, no LDS -> 8 blocks/CU, 32 waves/CU. 8-deep ILP on the xb row gathers.
__launch_bounds__(256)
__global__ void accum_kernel(const unsigned* __restrict__ rec, const unsigned* __restrict__ cursor,
                             const unsigned short* __restrict__ xb, unsigned short* __restrict__ Pb) {
    int n = blockIdx.x * 4 + (threadIdx.x >> 6);   // grid covers exactly 50000 waves
    int lane = threadIdx.x & 63;
    int cnt = min((int)cursor[n], CAP);
    // stage this node's records (coalesced 4B x 64); lanes >= cnt hold a null record
    unsigned r = (lane < cnt) ? rec[((size_t)n << 6) + lane] : 0u;
    float acc = 0.f;
    for (int j = 0; j < cnt; j += 8) {
        unsigned rv[8]; float xv[8];
        #pragma unroll
        for (int t = 0; t < 8; ++t) rv[t] = __shfl(r, j + t);   // past-cnt lanes -> null rec (s=0,c=0)
        #pragma unroll
        for (int t = 0; t < 8; ++t) xv[t] = bf2f(xb[(size_t)(rv[t] & 0xFFFFu) * 64 + lane]);
        #pragma unroll
        for (int t = 0; t < 8; ++t) acc = fmaf(bf2f((unsigned short)(rv[t] >> 16)), xv[t], acc);
    }
    Pb[(size_t)n * 64 + lane] = f2bf(acc);
}

// ---------------- fused dense (MFMA, persistent): gates GEMM + GRU + linear + L2-normalize ----------------
__launch_bounds__(256, 2)
__global__ void dense_kernel(const unsigned short* __restrict__ xb, const unsigned short* __restrict__ Pb,
                             const unsigned short* __restrict__ Bt, const unsigned short* __restrict__ Wlt,
                             const float* __restrict__ bzc, const float* __restrict__ blc,
                             float* __restrict__ out) {
    __shared__ unsigned short Bs[128 * 136];
    __shared__ unsigned short Wls[32 * 80];
    __shared__ unsigned short Hs[4][16 * 80];
    __shared__ float bzs[128], bls[32];

    int tid = threadIdx.x;
    for (int c = tid; c < 4096; c += 256) {
        int n = c >> 5; int k4 = (c & 31) * 4;
        *(uint2*)&Bs[n * 136 + k4] = *(const uint2*)&Bt[n * 128 + k4];
    }
    for (int c = tid; c < 512; c += 256) {
        int n = c >> 4; int k4 = (c & 15) * 4;
        *(uint2*)&Wls[n * 80 + k4] = *(const uint2*)&Wlt[n * 64 + k4];
    }
    if (tid < 128) bzs[tid] = bzc[tid];
    if (tid < 32) bls[tid] = blc[tid];
    __syncthreads();

    int wv = tid >> 6, lane = tid & 63;
    int nl = lane & 15, q = lane >> 4;
    int ngroups = (N_NODES + 63) / 64;

    for (int g = blockIdx.x; g < ngroups; g += gridDim.x) {
        int rowbase = g * 64 + wv * 16;
        int arow = rowbase + nl; if (arow >= N_NODES) arow = N_NODES - 1;

        v4f acc[8];
        #pragma unroll
        for (int i = 0; i < 8; ++i) acc[i] = (v4f)(0.f);

        #pragma unroll
        for (int kk = 0; kk < 4; ++kk) {
            int k0 = kk * 32 + q * 8;
            const unsigned short* ap = (kk < 2) ? (xb + (size_t)arow * 64 + k0)
                                                : (Pb + (size_t)arow * 64 + (k0 - 64));
            v8bf a = *(const v8bf*)ap;
            #pragma unroll
            for (int tn = 0; tn < 8; ++tn) {
                v8bf b = *(const v8bf*)&Bs[(tn * 16 + nl) * 136 + kk * 32 + q * 8];
                acc[tn] = __builtin_amdgcn_mfma_f32_16x16x32_bf16(a, b, acc[tn], 0, 0, 0);
            }
        }

        #pragma unroll
        for (int tn = 0; tn < 4; ++tn) {
            int n = tn * 16 + nl;
            float bz = bzs[n], bh = bzs[64 + n];
            #pragma unroll
            for (int r = 0; r < 4; ++r) {
                float z = acc[tn][r] + bz;
                float h = acc[tn + 4][r] + bh;
                float sg = 1.f / (1.f + __expf(-z));
                float th = 1.f - 2.f / (__expf(2.f * h) + 1.f);
                int m = q * 4 + r;
                Hs[wv][m * 80 + n] = f2bf((1.f - sg) * th);
            }
        }
        // Hs[wv] is wave-private; compiler's lgkmcnt ordering covers write->read

        v4f acc2[2];
        acc2[0] = (v4f)(0.f); acc2[1] = (v4f)(0.f);
        #pragma unroll
        for (int kk = 0; kk < 2; ++kk) {
            v8bf a = *(const v8bf*)&Hs[wv][nl * 80 + kk * 32 + q * 8];
            #pragma unroll
            for (int tn = 0; tn < 2; ++tn) {
                v8bf b = *(const v8bf*)&Wls[(tn * 16 + nl) * 80 + kk * 32 + q * 8];
                acc2[tn] = __builtin_amdgcn_mfma_f32_16x16x32_bf16(a, b, acc2[tn], 0, 0, 0);
            }
        }

        float o0[4], o1[4];
        #pragma unroll
        for (int r = 0; r < 4; ++r) {
            o0[r] = acc2[0][r] + bls[nl];
            o1[r] = acc2[1][r] + bls[16 + nl];
        }
        #pragma unroll
        for (int r = 0; r < 4; ++r) {
            float ss = o0[r] * o0[r] + o1[r] * o1[r];
            ss += __shfl_xor(ss, 1);
            ss += __shfl_xor(ss, 2);
            ss += __shfl_xor(ss, 4);
            ss += __shfl_xor(ss, 8);
            float dn = fmaxf(sqrtf(ss), 1e-12f);
            int node = rowbase + q * 4 + r;
            if (node < N_NODES) {
                out[node * 32 + nl] = o0[r] / dn;
                out[node * 32 + 16 + nl] = o1[r] / dn;
            }
        }
    }
}

extern "C" void kernel_launch(void* const* d_in, const int* in_sizes, int n_in,
                              void* d_out, int out_size, void* d_ws, size_t ws_size,
                              hipStream_t stream) {
    const float* x    = (const float*)d_in[0];
    const int*   ei   = (const int*)d_in[1];
    const float* ew   = (const float*)d_in[2];
    const float* Wxz0 = (const float*)d_in[3];
    const float* Wxz1 = (const float*)d_in[4];
    const float* bxz  = (const float*)d_in[5];
    const float* bhz  = (const float*)d_in[8];
    const float* Wxh0 = (const float*)d_in[15];
    const float* Wxh1 = (const float*)d_in[16];
    const float* bxh  = (const float*)d_in[17];
    const float* bhh  = (const float*)d_in[20];
    const float* Wlin = (const float*)d_in[21];
    const float* blin = (const float*)d_in[22];
    float* out = (float*)d_out;

    int E = in_sizes[2];
    const int* src = ei;
    const int* dst = ei + E;

    // workspace layout (bytes) — all regions DISJOINT (no overlays; ws >= 256 MiB):
    // [0, 200000)              dinv   (f32 N)
    // [200000, 6600000)        xb     (bf16 N*64)
    // [6600000, 13000000)      Pb     (bf16 N*64)
    // [13000000, 25800000)     partW  (f32 64 x N)
    // [25800000, 32200000)     partC  (u16 64 x N)
    // [32200000, 45000000)     rec    (u32 N*CAP)
    // [45000000, 45100000)     Bt | Wlt | bzc | blc
    // [45100000, 45300000)     cursor (u32 N)
    char* base = (char*)d_ws;
    float*          dinv   = (float*)(base + 0);
    unsigned short* xb     = (unsigned short*)(base + 200000);
    unsigned short* Pb     = (unsigned short*)(base + 6600000);
    float*          partW  = (float*)(base + 13000000);
    unsigned short* partC  = (unsigned short*)(base + 25800000);
    unsigned*       rec    = (unsigned*)(base + 32200000);
    char* p = base + 45000000;
    unsigned short* Bt     = (unsigned short*)p;      p += 128 * 128 * 2;
    unsigned short* Wlt    = (unsigned short*)p;      p += 32 * 64 * 2;
    float*          bzc    = (float*)p;               p += 128 * 4;
    float*          blc    = (float*)p;
    unsigned*       cursor = (unsigned*)(base + 45100000);

    const float4* x4 = (const float4*)x;
    uint2*        xb4 = (uint2*)xb;

    void* kargs[] = {
        (void*)&x4, (void*)&xb4, (void*)&src, (void*)&dst, (void*)&ew,
        (void*)&Wxz0, (void*)&Wxz1, (void*)&Wxh0, (void*)&Wxh1, (void*)&Wlin,
        (void*)&bxz, (void*)&bhz, (void*)&bxh, (void*)&bhh, (void*)&blin,
        (void*)&Bt, (void*)&Wlt, (void*)&bzc, (void*)&blc,
        (void*)&partW, (void*)&partC, (void*)&dinv, (void*)&cursor,
        (void*)&rec, (void*)&E
    };
    hipLaunchCooperativeKernel((const void*)coop_kernel, dim3(256), dim3(1024),
                               kargs, 0, stream);

    accum_kernel<<<N_NODES / 4, 256, 0, stream>>>(rec, cursor, xb, Pb);

    dense_kernel<<<512, 256, 0, stream>>>(xb, Pb, Bt, Wlt, bzc, blc, out);
}

// Round 4
// 216.264 us; speedup vs baseline: 1.3757x; 1.3757x over previous
//
#include <hip/hip_runtime.h>
#include <math.h>

#define N_NODES 50000
#define F 64
#define OUTF 32
#define NX4 (N_NODES * 16)          // float4 count of x
#define NPREP (16384 + 2048 + 128 + 32)
#define CAP 64                      // max in-degree capacity (in-deg ~Poisson(16); P(>64) ~ 1e-19)

#define CH 64                       // edge chunks (hists + place)
#define WHALF 25000                 // W-hist nodes per half (100 KB LDS f32)
#define CSPL 4                      // C/place node splits (packed u16 counters)
#define CR 12500                    // nodes per C split
#define CRW 6250                    // packed u32 words per C split (25 KB LDS)

typedef __bf16 v8bf __attribute__((ext_vector_type(8)));
typedef float v4f __attribute__((ext_vector_type(4)));

static __device__ __forceinline__ unsigned short f2bf(float f) {
    union { float f; unsigned u; } v; v.f = f;
    unsigned r = v.u + 0x7FFFu + ((v.u >> 16) & 1u);   // round-to-nearest-even
    return (unsigned short)(r >> 16);
}
static __device__ __forceinline__ float bf2f(unsigned short h) {
    union { unsigned u; float f; } v; v.u = ((unsigned)h) << 16;
    return v.f;
}

// ============ prehist: x->bf16 + weight prep (grid-stride) THEN histograms ============
// 384 blocks x 1024: blocks [0,128) weighted src-degree (64 chunks x 2 halves, 100KB f32);
// blocks [128,384) dst counts (64 chunks x 4 splits, packed u16 pairs in 25KB).
__launch_bounds__(1024)
__global__ void prehist_kernel(const float4* __restrict__ x4, uint2* __restrict__ xb4,
                               const int* __restrict__ src, const int* __restrict__ dst,
                               const float* __restrict__ ew,
                               const float* __restrict__ Wxz0, const float* __restrict__ Wxz1,
                               const float* __restrict__ Wxh0, const float* __restrict__ Wxh1,
                               const float* __restrict__ Wlin,
                               const float* __restrict__ bxz, const float* __restrict__ bhz,
                               const float* __restrict__ bxh, const float* __restrict__ bhh,
                               const float* __restrict__ blin,
                               unsigned short* __restrict__ Bt, unsigned short* __restrict__ Wlt,
                               float* __restrict__ bzc, float* __restrict__ blc,
                               float* __restrict__ partW, unsigned short* __restrict__ partC,
                               int E) {
    __shared__ float smf[WHALF];     // 100 KB; C-blocks use first 25 KB as u32
    unsigned* smu = (unsigned*)smf;
    int tid = threadIdx.x, b = blockIdx.x;

    // ---- phase 0: pre (grid-stride, independent of hist phase) ----
    for (int i = b * 1024 + tid; i < NX4 + NPREP; i += 384 * 1024) {
        if (i < NX4) {
            float4 v = x4[i];
            uint2 o;
            o.x = (unsigned)f2bf(v.x) | ((unsigned)f2bf(v.y) << 16);
            o.y = (unsigned)f2bf(v.z) | ((unsigned)f2bf(v.w) << 16);
            xb4[i] = o;
        } else {
            int idx = i - NX4;
            if (idx < 16384) {
                int k = idx & 127, n = idx >> 7;
                float v;
                if (k < 64) v = (n < 64) ? Wxz0[k * 64 + n] : Wxh0[k * 64 + (n - 64)];
                else        v = (n < 64) ? Wxz1[(k - 64) * 64 + n] : Wxh1[(k - 64) * 64 + (n - 64)];
                Bt[n * 128 + k] = f2bf(v);
            } else if (idx < 16384 + 2048) {
                int j = idx - 16384; int k = j & 63, n = j >> 6;
                Wlt[n * 64 + k] = f2bf(Wlin[k * 32 + n]);
            } else if (idx < 16384 + 2048 + 128) {
                int j = idx - 16384 - 2048;
                bzc[j] = (j < 64) ? (bxz[j] + bhz[j]) : (bxh[j - 64] + bhh[j - 64]);
            } else if (idx < NPREP) {
                int j = idx - 16384 - 2048 - 128;
                blc[j] = blin[j];
            }
        }
    }

    int epb = (E + CH - 1) / CH;
    if (b < 128) {
        // ---- weighted src-degree histogram ----
        int chunk = b >> 1, half = b & 1;
        int nbase = half * WHALF;
        int lo = chunk * epb, hi = min(lo + epb, E);
        for (int i = tid; i < WHALF; i += 1024) smf[i] = 0.f;
        __syncthreads();
        for (int e = lo + tid; e < hi; e += 1024) {
            int s = src[e];
            unsigned ls = (unsigned)(s - nbase);
            if (ls < WHALF) atomicAdd(&smf[ls], ew[e]);
        }
        __syncthreads();
        for (int i = tid; i < WHALF; i += 1024)
            partW[(size_t)chunk * N_NODES + nbase + i] = smf[i];
    } else {
        // ---- dst-count histogram (packed u16 pairs) ----
        int b2 = b - 128;                 // 0..255
        int chunk = b2 >> 2, split = b2 & 3;
        int nbase = split * CR;
        int lo = chunk * epb, hi = min(lo + epb, E);
        for (int i = tid; i < CRW; i += 1024) smu[i] = 0u;
        __syncthreads();
        for (int e = lo + tid; e < hi; e += 1024) {
            unsigned ls = (unsigned)(dst[e] - nbase);
            if (ls < CR) atomicAdd(&smu[ls >> 1], 1u << ((ls & 1) << 4));
        }
        __syncthreads();
        unsigned* pc32 = (unsigned*)partC + (((size_t)chunk * N_NODES + nbase) >> 1);
        for (int i = tid; i < CRW; i += 1024) pc32[i] = smu[i];
    }
}

// ---------------- reduceW: deg reduce -> dinv; exclusive prefix of partC -> offsets + cursor ----------------
__global__ void reducew_kernel(const float* __restrict__ partW, unsigned short* __restrict__ partC,
                               float* __restrict__ dinv, unsigned* __restrict__ cursor) {
    int i = blockIdx.x * 256 + threadIdx.x;
    if (i >= N_NODES) return;
    float s = 0.f;
    #pragma unroll
    for (int c = 0; c < CH; ++c) s += partW[(size_t)c * N_NODES + i];
    dinv[i] = s > 0.f ? rsqrtf(s) : 0.f;
    unsigned run = 0u;
    #pragma unroll
    for (int c = 0; c < CH; ++c) {
        unsigned v = partC[(size_t)c * N_NODES + i];
        partC[(size_t)c * N_NODES + i] = (unsigned short)run;   // exclusive prefix (per-chunk start)
        run += v;
    }
    cursor[i] = run;                            // total in-degree (dense clamps to CAP)
}

// ---------------- place: deterministic CSR build, packed-u16 LDS cursors, NO global atomics ----------------
__launch_bounds__(1024)
__global__ void place_kernel(const int* __restrict__ src, const int* __restrict__ dst,
                             const float* __restrict__ w, const float* __restrict__ dinv,
                             const unsigned short* __restrict__ offs, unsigned* __restrict__ rec, int E) {
    __shared__ unsigned curs[CRW];   // 25 KB, two u16 cursors per word
    int b = blockIdx.x, tid = threadIdx.x;
    int chunk = b >> 2, split = b & 3;
    int nbase = split * CR;
    const unsigned* offs32 = (const unsigned*)offs + (((size_t)chunk * N_NODES + nbase) >> 1);
    for (int i = tid; i < CRW; i += 1024) curs[i] = offs32[i];
    __syncthreads();
    int epb = (E + CH - 1) / CH;
    int lo = chunk * epb, hi = min(lo + epb, E);
    for (int e = lo + tid; e < hi; e += 1024) {
        int d = dst[e];
        unsigned ls = (unsigned)(d - nbase);
        if (ls < CR) {
            int s = src[e];
            float coef = -dinv[s] * w[e] * dinv[d];
            unsigned sh = (ls & 1) << 4;
            unsigned old = atomicAdd(&curs[ls >> 1], 1u << sh);   // LDS atomic, packed halves
            unsigned pos = (old >> sh) & 0xFFFFu;
            if (pos < CAP)
                rec[((size_t)d << 6) + pos] = (unsigned)s | ((unsigned)f2bf(coef) << 16);
        }
    }
}

// ---------------- fused dense: per-group accum (gather) + gates GEMM + GRU + linear + L2-norm ----------------
__launch_bounds__(256, 2)
__global__ void dense_kernel(const unsigned short* __restrict__ xb,
                             const unsigned* __restrict__ rec, const unsigned* __restrict__ cursor,
                             const unsigned short* __restrict__ Bt, const unsigned short* __restrict__ Wlt,
                             const float* __restrict__ bzc, const float* __restrict__ blc,
                             float* __restrict__ out) {
    __shared__ unsigned short Bs[128 * 136];
    __shared__ unsigned short Wls[32 * 80];
    __shared__ unsigned short Hs[4][16 * 80];
    __shared__ unsigned short Ps[4][16 * 80];   // per-wave Pb tile (gather-accumulated)
    __shared__ float bzs[128], bls[32];

    int tid = threadIdx.x;
    for (int c = tid; c < 4096; c += 256) {
        int n = c >> 5; int k4 = (c & 31) * 4;
        *(uint2*)&Bs[n * 136 + k4] = *(const uint2*)&Bt[n * 128 + k4];
    }
    for (int c = tid; c < 512; c += 256) {
        int n = c >> 4; int k4 = (c & 15) * 4;
        *(uint2*)&Wls[n * 80 + k4] = *(const uint2*)&Wlt[n * 64 + k4];
    }
    if (tid < 128) bzs[tid] = bzc[tid];
    if (tid < 32) bls[tid] = blc[tid];
    __syncthreads();

    int wv = tid >> 6, lane = tid & 63;
    int nl = lane & 15, q = lane >> 4;
    int ngroups = (N_NODES + 63) / 64;

    for (int g = blockIdx.x; g < ngroups; g += gridDim.x) {
        int rowbase = g * 64 + wv * 16;
        int arow = rowbase + nl; if (arow >= N_NODES) arow = N_NODES - 1;

        // ---- accum: gather-sum the 16 Pb rows this wave owns into Ps[wv] ----
        #pragma unroll 2
        for (int m = 0; m < 16; ++m) {
            int n = rowbase + m;
            float acc = 0.f;
            if (n < N_NODES) {
                int cnt = min((int)cursor[n], CAP);
                unsigned r = (lane < cnt) ? rec[((size_t)n << 6) + lane] : 0u;
                for (int j = 0; j < cnt; j += 8) {
                    unsigned rv[8]; float xv[8];
                    #pragma unroll
                    for (int t = 0; t < 8; ++t) rv[t] = __shfl(r, j + t);  // past-cnt -> null rec
                    #pragma unroll
                    for (int t = 0; t < 8; ++t) xv[t] = bf2f(xb[(size_t)(rv[t] & 0xFFFFu) * 64 + lane]);
                    #pragma unroll
                    for (int t = 0; t < 8; ++t) acc = fmaf(bf2f((unsigned short)(rv[t] >> 16)), xv[t], acc);
                }
            }
            Ps[wv][m * 80 + lane] = f2bf(acc);
        }
        // Ps[wv] is wave-private; compiler's lgkmcnt ordering covers write->read

        v4f acc[8];
        #pragma unroll
        for (int i = 0; i < 8; ++i) acc[i] = (v4f)(0.f);

        #pragma unroll
        for (int kk = 0; kk < 4; ++kk) {
            int k0 = kk * 32 + q * 8;
            v8bf a;
            if (kk < 2) a = *(const v8bf*)(xb + (size_t)arow * 64 + k0);
            else        a = *(const v8bf*)&Ps[wv][nl * 80 + (k0 - 64)];
            #pragma unroll
            for (int tn = 0; tn < 8; ++tn) {
                v8bf b = *(const v8bf*)&Bs[(tn * 16 + nl) * 136 + kk * 32 + q * 8];
                acc[tn] = __builtin_amdgcn_mfma_f32_16x16x32_bf16(a, b, acc[tn], 0, 0, 0);
            }
        }

        #pragma unroll
        for (int tn = 0; tn < 4; ++tn) {
            int n = tn * 16 + nl;
            float bz = bzs[n], bh = bzs[64 + n];
            #pragma unroll
            for (int r = 0; r < 4; ++r) {
                float z = acc[tn][r] + bz;
                float h = acc[tn + 4][r] + bh;
                float sg = 1.f / (1.f + __expf(-z));
                float th = 1.f - 2.f / (__expf(2.f * h) + 1.f);
                int m = q * 4 + r;
                Hs[wv][m * 80 + n] = f2bf((1.f - sg) * th);
            }
        }
        // Hs[wv] is wave-private; compiler's lgkmcnt ordering covers write->read

        v4f acc2[2];
        acc2[0] = (v4f)(0.f); acc2[1] = (v4f)(0.f);
        #pragma unroll
        for (int kk = 0; kk < 2; ++kk) {
            v8bf a = *(const v8bf*)&Hs[wv][nl * 80 + kk * 32 + q * 8];
            #pragma unroll
            for (int tn = 0; tn < 2; ++tn) {
                v8bf b = *(const v8bf*)&Wls[(tn * 16 + nl) * 80 + kk * 32 + q * 8];
                acc2[tn] = __builtin_amdgcn_mfma_f32_16x16x32_bf16(a, b, acc2[tn], 0, 0, 0);
            }
        }

        float o0[4], o1[4];
        #pragma unroll
        for (int r = 0; r < 4; ++r) {
            o0[r] = acc2[0][r] + bls[nl];
            o1[r] = acc2[1][r] + bls[16 + nl];
        }
        #pragma unroll
        for (int r = 0; r < 4; ++r) {
            float ss = o0[r] * o0[r] + o1[r] * o1[r];
            ss += __shfl_xor(ss, 1);
            ss += __shfl_xor(ss, 2);
            ss += __shfl_xor(ss, 4);
            ss += __shfl_xor(ss, 8);
            float dn = fmaxf(sqrtf(ss), 1e-12f);
            int node = rowbase + q * 4 + r;
            if (node < N_NODES) {
                out[node * 32 + nl] = o0[r] / dn;
                out[node * 32 + 16 + nl] = o1[r] / dn;
            }
        }
    }
}

extern "C" void kernel_launch(void* const* d_in, const int* in_sizes, int n_in,
                              void* d_out, int out_size, void* d_ws, size_t ws_size,
                              hipStream_t stream) {
    const float* x    = (const float*)d_in[0];
    const int*   ei   = (const int*)d_in[1];
    const float* ew   = (const float*)d_in[2];
    const float* Wxz0 = (const float*)d_in[3];
    const float* Wxz1 = (const float*)d_in[4];
    const float* bxz  = (const float*)d_in[5];
    const float* bhz  = (const float*)d_in[8];
    const float* Wxh0 = (const float*)d_in[15];
    const float* Wxh1 = (const float*)d_in[16];
    const float* bxh  = (const float*)d_in[17];
    const float* bhh  = (const float*)d_in[20];
    const float* Wlin = (const float*)d_in[21];
    const float* blin = (const float*)d_in[22];
    float* out = (float*)d_out;

    int E = in_sizes[2];
    const int* src = ei;
    const int* dst = ei + E;

    // workspace layout (bytes) — all regions DISJOINT:
    // [0, 200000)              dinv   (f32 N)
    // [200000, 6600000)        xb     (bf16 N*64)
    // [6600000, 19400000)      partW  (f32 64 x N)
    // [19400000, 25800000)     partC  (u16 64 x N)
    // [25800000, 38600000)     rec    (u32 N*CAP)
    // [38600000, 38700000)     Bt | Wlt | bzc | blc
    // [38700000, 38900000)     cursor (u32 N)
    char* base = (char*)d_ws;
    float*          dinv   = (float*)(base + 0);
    unsigned short* xb     = (unsigned short*)(base + 200000);
    float*          partW  = (float*)(base + 6600000);
    unsigned short* partC  = (unsigned short*)(base + 19400000);
    unsigned*       rec    = (unsigned*)(base + 25800000);
    char* p = base + 38600000;
    unsigned short* Bt     = (unsigned short*)p;      p += 128 * 128 * 2;
    unsigned short* Wlt    = (unsigned short*)p;      p += 32 * 64 * 2;
    float*          bzc    = (float*)p;               p += 128 * 4;
    float*          blc    = (float*)p;
    unsigned*       cursor = (unsigned*)(base + 38700000);

    prehist_kernel<<<384, 1024, 0, stream>>>(
        (const float4*)x, (uint2*)xb, src, dst, ew,
        Wxz0, Wxz1, Wxh0, Wxh1, Wlin, bxz, bhz, bxh, bhh, blin,
        Bt, Wlt, bzc, blc, partW, partC, E);

    reducew_kernel<<<(N_NODES + 255) / 256, 256, 0, stream>>>(partW, partC, dinv, cursor);

    place_kernel<<<CH * CSPL, 1024, 0, stream>>>(src, dst, ew, dinv, partC, rec, E);

    dense_kernel<<<512, 256, 0, stream>>>(xb, rec, cursor, Bt, Wlt, bzc, blc, out);
}

// Round 5
// 180.904 us; speedup vs baseline: 1.6446x; 1.1955x over previous
//
#include <hip/hip_runtime.h>
#include <math.h>

#define N_NODES 50000
#define F 64
#define OUTF 32
#define NX4 (N_NODES * 16)          // float4 count of x
#define NPREP (16384 + 2048 + 128 + 32)
#define CAP 64                      // max in-degree capacity (in-deg ~Poisson(16); P(>64) ~ 1e-19)

#define CH 64                       // edge chunks (hists + place)
#define WHALF 25000                 // W-hist nodes per half (100 KB LDS f32)
#define CSPL 4                      // C/place node splits (packed u16 counters)
#define CR 12500                    // nodes per C split
#define CRW 6250                    // packed u32 words per C split (25 KB LDS)

typedef __bf16 v8bf __attribute__((ext_vector_type(8)));
typedef float v4f __attribute__((ext_vector_type(4)));

static __device__ __forceinline__ unsigned short f2bf(float f) {
    union { float f; unsigned u; } v; v.f = f;
    unsigned r = v.u + 0x7FFFu + ((v.u >> 16) & 1u);   // round-to-nearest-even
    return (unsigned short)(r >> 16);
}
static __device__ __forceinline__ float bf2f(unsigned short h) {
    union { unsigned u; float f; } v; v.u = ((unsigned)h) << 16;
    return v.f;
}

// ============ prehist: x->bf16 + weight prep (grid-stride) THEN histograms ============
// 384 blocks x 1024: blocks [0,128) weighted src-degree (64 chunks x 2 halves, 100KB f32);
// blocks [128,384) dst counts (64 chunks x 4 splits, packed u16 pairs in 25KB).
__launch_bounds__(1024)
__global__ void prehist_kernel(const float4* __restrict__ x4, uint2* __restrict__ xb4,
                               const int* __restrict__ src, const int* __restrict__ dst,
                               const float* __restrict__ ew,
                               const float* __restrict__ Wxz0, const float* __restrict__ Wxz1,
                               const float* __restrict__ Wxh0, const float* __restrict__ Wxh1,
                               const float* __restrict__ Wlin,
                               const float* __restrict__ bxz, const float* __restrict__ bhz,
                               const float* __restrict__ bxh, const float* __restrict__ bhh,
                               const float* __restrict__ blin,
                               unsigned short* __restrict__ Bt, unsigned short* __restrict__ Wlt,
                               float* __restrict__ bzc, float* __restrict__ blc,
                               float* __restrict__ partW, unsigned short* __restrict__ partC,
                               int E) {
    __shared__ float smf[WHALF];     // 100 KB; C-blocks use first 25 KB as u32
    unsigned* smu = (unsigned*)smf;
    int tid = threadIdx.x, b = blockIdx.x;

    // ---- phase 0: pre (grid-stride, independent of hist phase) ----
    for (int i = b * 1024 + tid; i < NX4 + NPREP; i += 384 * 1024) {
        if (i < NX4) {
            float4 v = x4[i];
            uint2 o;
            o.x = (unsigned)f2bf(v.x) | ((unsigned)f2bf(v.y) << 16);
            o.y = (unsigned)f2bf(v.z) | ((unsigned)f2bf(v.w) << 16);
            xb4[i] = o;
        } else {
            int idx = i - NX4;
            if (idx < 16384) {
                int k = idx & 127, n = idx >> 7;
                float v;
                if (k < 64) v = (n < 64) ? Wxz0[k * 64 + n] : Wxh0[k * 64 + (n - 64)];
                else        v = (n < 64) ? Wxz1[(k - 64) * 64 + n] : Wxh1[(k - 64) * 64 + (n - 64)];
                Bt[n * 128 + k] = f2bf(v);
            } else if (idx < 16384 + 2048) {
                int j = idx - 16384; int k = j & 63, n = j >> 6;
                Wlt[n * 64 + k] = f2bf(Wlin[k * 32 + n]);
            } else if (idx < 16384 + 2048 + 128) {
                int j = idx - 16384 - 2048;
                bzc[j] = (j < 64) ? (bxz[j] + bhz[j]) : (bxh[j - 64] + bhh[j - 64]);
            } else if (idx < NPREP) {
                int j = idx - 16384 - 2048 - 128;
                blc[j] = blin[j];
            }
        }
    }

    int epb = (E + CH - 1) / CH;
    if (b < 128) {
        // ---- weighted src-degree histogram ----
        int chunk = b >> 1, half = b & 1;
        int nbase = half * WHALF;
        int lo = chunk * epb, hi = min(lo + epb, E);
        for (int i = tid; i < WHALF; i += 1024) smf[i] = 0.f;
        __syncthreads();
        for (int e = lo + tid; e < hi; e += 1024) {
            int s = src[e];
            unsigned ls = (unsigned)(s - nbase);
            if (ls < WHALF) atomicAdd(&smf[ls], ew[e]);
        }
        __syncthreads();
        for (int i = tid; i < WHALF; i += 1024)
            partW[(size_t)chunk * N_NODES + nbase + i] = smf[i];
    } else {
        // ---- dst-count histogram (packed u16 pairs) ----
        int b2 = b - 128;                 // 0..255
        int chunk = b2 >> 2, split = b2 & 3;
        int nbase = split * CR;
        int lo = chunk * epb, hi = min(lo + epb, E);
        for (int i = tid; i < CRW; i += 1024) smu[i] = 0u;
        __syncthreads();
        for (int e = lo + tid; e < hi; e += 1024) {
            unsigned ls = (unsigned)(dst[e] - nbase);
            if (ls < CR) atomicAdd(&smu[ls >> 1], 1u << ((ls & 1) << 4));
        }
        __syncthreads();
        unsigned* pc32 = (unsigned*)partC + (((size_t)chunk * N_NODES + nbase) >> 1);
        for (int i = tid; i < CRW; i += 1024) pc32[i] = smu[i];
    }
}

// ---------------- reduceW: deg reduce -> dinv; exclusive prefix of partC -> offsets + cursor ----------------
__global__ void reducew_kernel(const float* __restrict__ partW, unsigned short* __restrict__ partC,
                               float* __restrict__ dinv, unsigned* __restrict__ cursor) {
    int i = blockIdx.x * 256 + threadIdx.x;
    if (i >= N_NODES) return;
    float s = 0.f;
    #pragma unroll
    for (int c = 0; c < CH; ++c) s += partW[(size_t)c * N_NODES + i];
    dinv[i] = s > 0.f ? rsqrtf(s) : 0.f;
    unsigned run = 0u;
    #pragma unroll
    for (int c = 0; c < CH; ++c) {
        unsigned v = partC[(size_t)c * N_NODES + i];
        partC[(size_t)c * N_NODES + i] = (unsigned short)run;   // exclusive prefix (per-chunk start)
        run += v;
    }
    cursor[i] = run;                            // total in-degree (accum clamps to CAP)
}

// ---------------- place: deterministic CSR build, packed-u16 LDS cursors, NO global atomics ----------------
__launch_bounds__(1024)
__global__ void place_kernel(const int* __restrict__ src, const int* __restrict__ dst,
                             const float* __restrict__ w, const float* __restrict__ dinv,
                             const unsigned short* __restrict__ offs, unsigned* __restrict__ rec, int E) {
    __shared__ unsigned curs[CRW];   // 25 KB, two u16 cursors per word
    int b = blockIdx.x, tid = threadIdx.x;
    int chunk = b >> 2, split = b & 3;
    int nbase = split * CR;
    const unsigned* offs32 = (const unsigned*)offs + (((size_t)chunk * N_NODES + nbase) >> 1);
    for (int i = tid; i < CRW; i += 1024) curs[i] = offs32[i];
    __syncthreads();
    int epb = (E + CH - 1) / CH;
    int lo = chunk * epb, hi = min(lo + epb, E);
    for (int e = lo + tid; e < hi; e += 1024) {
        int d = dst[e];
        unsigned ls = (unsigned)(d - nbase);
        if (ls < CR) {
            int s = src[e];
            float coef = -dinv[s] * w[e] * dinv[d];
            unsigned sh = (ls & 1) << 4;
            unsigned old = atomicAdd(&curs[ls >> 1], 1u << sh);   // LDS atomic, packed halves
            unsigned pos = (old >> sh) & 0xFFFFu;
            if (pos < CAP)
                rec[((size_t)d << 6) + pos] = (unsigned)s | ((unsigned)f2bf(coef) << 16);
        }
    }
}

// ---------------- accum: one wave per dst node, gather + f32 register accumulate ----------------
// 4 nodes/block, no LDS -> 8 blocks/CU, 32 waves/CU (max TLP for the latency-bound gather).
__launch_bounds__(256)
__global__ void accum_kernel(const unsigned* __restrict__ rec, const unsigned* __restrict__ cursor,
                             const unsigned short* __restrict__ xb, unsigned short* __restrict__ Pb) {
    int n = blockIdx.x * 4 + (threadIdx.x >> 6);   // grid covers exactly 50000 waves
    int lane = threadIdx.x & 63;
    int cnt = min((int)cursor[n], CAP);
    // stage this node's records (coalesced 4B x 64); lanes >= cnt hold a null record
    unsigned r = (lane < cnt) ? rec[((size_t)n << 6) + lane] : 0u;
    float acc = 0.f;
    for (int j = 0; j < cnt; j += 8) {
        unsigned rv[8]; float xv[8];
        #pragma unroll
        for (int t = 0; t < 8; ++t) rv[t] = __shfl(r, j + t);   // past-cnt lanes -> null rec (s=0,c=0)
        #pragma unroll
        for (int t = 0; t < 8; ++t) xv[t] = bf2f(xb[(size_t)(rv[t] & 0xFFFFu) * 64 + lane]);
        #pragma unroll
        for (int t = 0; t < 8; ++t) acc = fmaf(bf2f((unsigned short)(rv[t] >> 16)), xv[t], acc);
    }
    Pb[(size_t)n * 64 + lane] = f2bf(acc);
}

// ---------------- fused dense (MFMA, persistent): gates GEMM + GRU + linear + L2-normalize ----------------
__launch_bounds__(256, 2)
__global__ void dense_kernel(const unsigned short* __restrict__ xb, const unsigned short* __restrict__ Pb,
                             const unsigned short* __restrict__ Bt, const unsigned short* __restrict__ Wlt,
                             const float* __restrict__ bzc, const float* __restrict__ blc,
                             float* __restrict__ out) {
    __shared__ unsigned short Bs[128 * 136];
    __shared__ unsigned short Wls[32 * 80];
    __shared__ unsigned short Hs[4][16 * 80];
    __shared__ float bzs[128], bls[32];

    int tid = threadIdx.x;
    for (int c = tid; c < 4096; c += 256) {
        int n = c >> 5; int k4 = (c & 31) * 4;
        *(uint2*)&Bs[n * 136 + k4] = *(const uint2*)&Bt[n * 128 + k4];
    }
    for (int c = tid; c < 512; c += 256) {
        int n = c >> 4; int k4 = (c & 15) * 4;
        *(uint2*)&Wls[n * 80 + k4] = *(const uint2*)&Wlt[n * 64 + k4];
    }
    if (tid < 128) bzs[tid] = bzc[tid];
    if (tid < 32) bls[tid] = blc[tid];
    __syncthreads();

    int wv = tid >> 6, lane = tid & 63;
    int nl = lane & 15, q = lane >> 4;
    int ngroups = (N_NODES + 63) / 64;

    for (int g = blockIdx.x; g < ngroups; g += gridDim.x) {
        int rowbase = g * 64 + wv * 16;
        int arow = rowbase + nl; if (arow >= N_NODES) arow = N_NODES - 1;

        v4f acc[8];
        #pragma unroll
        for (int i = 0; i < 8; ++i) acc[i] = (v4f)(0.f);

        #pragma unroll
        for (int kk = 0; kk < 4; ++kk) {
            int k0 = kk * 32 + q * 8;
            const unsigned short* ap = (kk < 2) ? (xb + (size_t)arow * 64 + k0)
                                                : (Pb + (size_t)arow * 64 + (k0 - 64));
            v8bf a = *(const v8bf*)ap;
            #pragma unroll
            for (int tn = 0; tn < 8; ++tn) {
                v8bf b = *(const v8bf*)&Bs[(tn * 16 + nl) * 136 + kk * 32 + q * 8];
                acc[tn] = __builtin_amdgcn_mfma_f32_16x16x32_bf16(a, b, acc[tn], 0, 0, 0);
            }
        }

        #pragma unroll
        for (int tn = 0; tn < 4; ++tn) {
            int n = tn * 16 + nl;
            float bz = bzs[n], bh = bzs[64 + n];
            #pragma unroll
            for (int r = 0; r < 4; ++r) {
                float z = acc[tn][r] + bz;
                float h = acc[tn + 4][r] + bh;
                float sg = 1.f / (1.f + __expf(-z));
                float th = 1.f - 2.f / (__expf(2.f * h) + 1.f);
                int m = q * 4 + r;
                Hs[wv][m * 80 + n] = f2bf((1.f - sg) * th);
            }
        }
        // Hs[wv] is wave-private; compiler's lgkmcnt ordering covers write->read

        v4f acc2[2];
        acc2[0] = (v4f)(0.f); acc2[1] = (v4f)(0.f);
        #pragma unroll
        for (int kk = 0; kk < 2; ++kk) {
            v8bf a = *(const v8bf*)&Hs[wv][nl * 80 + kk * 32 + q * 8];
            #pragma unroll
            for (int tn = 0; tn < 2; ++tn) {
                v8bf b = *(const v8bf*)&Wls[(tn * 16 + nl) * 80 + kk * 32 + q * 8];
                acc2[tn] = __builtin_amdgcn_mfma_f32_16x16x32_bf16(a, b, acc2[tn], 0, 0, 0);
            }
        }

        float o0[4], o1[4];
        #pragma unroll
        for (int r = 0; r < 4; ++r) {
            o0[r] = acc2[0][r] + bls[nl];
            o1[r] = acc2[1][r] + bls[16 + nl];
        }
        #pragma unroll
        for (int r = 0; r < 4; ++r) {
            float ss = o0[r] * o0[r] + o1[r] * o1[r];
            ss += __shfl_xor(ss, 1);
            ss += __shfl_xor(ss, 2);
            ss += __shfl_xor(ss, 4);
            ss += __shfl_xor(ss, 8);
            float dn = fmaxf(sqrtf(ss), 1e-12f);
            int node = rowbase + q * 4 + r;
            if (node < N_NODES) {
                out[node * 32 + nl] = o0[r] / dn;
                out[node * 32 + 16 + nl] = o1[r] / dn;
            }
        }
    }
}

extern "C" void kernel_launch(void* const* d_in, const int* in_sizes, int n_in,
                              void* d_out, int out_size, void* d_ws, size_t ws_size,
                              hipStream_t stream) {
    const float* x    = (const float*)d_in[0];
    const int*   ei   = (const int*)d_in[1];
    const float* ew   = (const float*)d_in[2];
    const float* Wxz0 = (const float*)d_in[3];
    const float* Wxz1 = (const float*)d_in[4];
    const float* bxz  = (const float*)d_in[5];
    const float* bhz  = (const float*)d_in[8];
    const float* Wxh0 = (const float*)d_in[15];
    const float* Wxh1 = (const float*)d_in[16];
    const float* bxh  = (const float*)d_in[17];
    const float* bhh  = (const float*)d_in[20];
    const float* Wlin = (const float*)d_in[21];
    const float* blin = (const float*)d_in[22];
    float* out = (float*)d_out;

    int E = in_sizes[2];
    const int* src = ei;
    const int* dst = ei + E;

    // workspace layout (bytes) — all regions DISJOINT:
    // [0, 200000)              dinv   (f32 N)
    // [200000, 6600000)        xb     (bf16 N*64)
    // [6600000, 13000000)      Pb     (bf16 N*64)
    // [13000000, 25800000)     partW  (f32 64 x N)
    // [25800000, 32200000)     partC  (u16 64 x N)
    // [32200000, 45000000)     rec    (u32 N*CAP)
    // [45000000, 45100000)     Bt | Wlt | bzc | blc
    // [45100000, 45300000)     cursor (u32 N)
    char* base = (char*)d_ws;
    float*          dinv   = (float*)(base + 0);
    unsigned short* xb     = (unsigned short*)(base + 200000);
    unsigned short* Pb     = (unsigned short*)(base + 6600000);
    float*          partW  = (float*)(base + 13000000);
    unsigned short* partC  = (unsigned short*)(base + 25800000);
    unsigned*       rec    = (unsigned*)(base + 32200000);
    char* p = base + 45000000;
    unsigned short* Bt     = (unsigned short*)p;      p += 128 * 128 * 2;
    unsigned short* Wlt    = (unsigned short*)p;      p += 32 * 64 * 2;
    float*          bzc    = (float*)p;               p += 128 * 4;
    float*          blc    = (float*)p;
    unsigned*       cursor = (unsigned*)(base + 45100000);

    prehist_kernel<<<384, 1024, 0, stream>>>(
        (const float4*)x, (uint2*)xb, src, dst, ew,
        Wxz0, Wxz1, Wxh0, Wxh1, Wlin, bxz, bhz, bxh, bhh, blin,
        Bt, Wlt, bzc, blc, partW, partC, E);

    reducew_kernel<<<(N_NODES + 255) / 256, 256, 0, stream>>>(partW, partC, dinv, cursor);

    place_kernel<<<CH * CSPL, 1024, 0, stream>>>(src, dst, ew, dinv, partC, rec, E);

    accum_kernel<<<N_NODES / 4, 256, 0, stream>>>(rec, cursor, xb, Pb);

    dense_kernel<<<512, 256, 0, stream>>>(xb, Pb, Bt, Wlt, bzc, blc, out);
}